// Round 9
// baseline (190.394 us; speedup 1.0000x reference)
//
#include <hip/hip_runtime.h>

// PPolyIntSoftmax, rows of 512. Exact float64-numpy replication.
// R16 (resubmit x2 — rounds 7+8 benches died on container acquisition; the
//  experiment has never run): sync-domain = 1 wave. 64-thread blocks; one
//  wave owns 4 CONTIGUOUS rows (rows 4b..4b+3 adjacent -> loads coalesced),
//  processed sequentially with depth-2 lookahead. LUT staged once per block
//  from the d_ws prebuilt copy (4x int4/thread, L2-hot). ZERO __syncthreads:
//  single-wave LDS producer->consumer is ordered by lgkmcnt alone.
//  Rationale: R9-R15 nulled VALU (R15), ILP (R12), NT stores (R14), stagger
//  (R13), persistence (R10) -- but EVERY variant kept a 4-wave barrier per
//  row-group, which forces block-wide vmcnt drain + phase-locked
//  load/compute/store bursts (constant ~2.5 TB/s HBM signature, invariant
//  to occupancy 28-65% and VALU 25-41%). This removes it.
//  32 independent 1-wave blocks/CU; ~2x bytes in flight; no convergence.
//  Exact-integer pipeline byte-identical to R15 (absmax=0): fdiv_floor
//  two-fma correction, LUT Horner (i32/i64), DPP i32 sum, __ddiv_rn factor,
//  (e*factor)>>25 u64, plain float4 stores.

#define ROWLEN 512

typedef float nfloat4 __attribute__((ext_vector_type(4)));

#define DPP_SUM_I32(t)                                                        \
    t += __builtin_amdgcn_update_dpp(0, t, 0x111, 0xf, 0xf, true);            \
    t += __builtin_amdgcn_update_dpp(0, t, 0x112, 0xf, 0xf, true);            \
    t += __builtin_amdgcn_update_dpp(0, t, 0x114, 0xf, 0xf, true);            \
    t += __builtin_amdgcn_update_dpp(0, t, 0x118, 0xf, 0xf, true);            \
    t += __builtin_amdgcn_update_dpp(0, t, 0x142, 0xa, 0xf, true);            \
    t += __builtin_amdgcn_update_dpp(0, t, 0x143, 0xc, 0xf, true);

#define DPP_MAX_F32_STEP(m, ctrl, rmask)                                      \
    {                                                                         \
        int _mi = __float_as_int(m);                                          \
        int _sh = __builtin_amdgcn_update_dpp(_mi, _mi, ctrl, rmask, 0xf, false); \
        m = fmaxf(m, __int_as_float(_sh));                                    \
    }
#define DPP_MIN_F32_STEP(m, ctrl, rmask)                                      \
    {                                                                         \
        int _mi = __float_as_int(m);                                          \
        int _sh = __builtin_amdgcn_update_dpp(_mi, _mi, ctrl, rmask, 0xf, false); \
        m = fminf(m, __int_as_float(_sh));                                    \
    }

// ---- one-block pre-kernel: build the 1024-entry exp_int LUT into d_ws ----
__global__ __launch_bounds__(256) void lut_builder(
    const float* __restrict__ cf, int* __restrict__ glut)
{
    const int tid = threadIdx.x;
    int4 ev;
    int* evp = reinterpret_cast<int*>(&ev);
    const int j0 = tid * 4;
    #pragma unroll
    for (int jj = 0; jj < 4; ++jj) {
        const int j  = j0 + jj;
        const int u  = j - 768;              // u = xi + 128
        const int uc = u < 0 ? 0 : u;
        int idx = ((uc + 1) * 257) >> 12;    // == clip(searchsorted-1,0,15)
        idx = idx > 15 ? 15 : idx;
        const int c0 = (int)cf[idx * 3 + 0];
        const int c1 = (int)cf[idx * 3 + 1];
        const int c2 = (int)cf[idx * 3 + 2];
        const int xi = j - 896;              // UNCLAMPED xi
        const int r1 = c2 * xi + c1;               // |c2*xi| < 2^27: exact i32
        long long r2 = (long long)r1 * xi + c0;    // exact i64
        if (r2 < 0) r2 = 0;
        evp[jj] = (int)(r2 >> 15);
    }
    reinterpret_cast<int4*>(glut)[tid] = ev;
}

__global__ __launch_bounds__(64, 8) void ppis_kernel(
    const float* __restrict__ x,
    const float* __restrict__ sfp,
    const float* __restrict__ lo,   // unused: structure derived analytically
    const float* __restrict__ cf,
    float* __restrict__ out,
    const int* __restrict__ glut,
    int has_glut,
    int nrows)
{
    __shared__ int  s_e[1024];   // exp_int LUT: entry j <-> xi = j - 896
    __shared__ int4 s_cf[16];    // coeffs for the rare exact-fallback path

    const int tid = threadIdx.x;             // == lane (1-wave block)

    // block b owns rows 4b..4b+3 (contiguous: 8KB region, loads coalesced)
    const long long row0 = (long long)blockIdx.x * 4;
    const float4* xp = reinterpret_cast<const float4*>(x) + row0 * (ROWLEN / 4);

    // ---- prologue: issue x row0/row1 loads + LUT loads; no barrier ever ----
    float4 a0 = xp[tid];
    float4 b0 = xp[tid + 64];
    float4 a1 = xp[128 + tid];
    float4 b1 = xp[128 + 64 + tid];

    const float s  = sfp[0];
    const float ry = 1.0f / s;   // approx reciprocal; exactness via fma sign tests

    if (tid < 16)
        s_cf[tid] = make_int4((int)cf[tid*3+0], (int)cf[tid*3+1], (int)cf[tid*3+2], 0);

    int4* se4 = reinterpret_cast<int4*>(s_e);
    if (has_glut) {
        const int4* g4 = reinterpret_cast<const int4*>(glut);
        int4 L0 = g4[tid], L1 = g4[tid + 64], L2 = g4[tid + 128], L3 = g4[tid + 192];
        se4[tid]       = L0;
        se4[tid + 64]  = L1;
        se4[tid + 128] = L2;
        se4[tid + 192] = L3;
    } else {
        // fallback: build in-kernel (bit-identical math), 16 entries/thread
        #pragma unroll
        for (int q = 0; q < 4; ++q) {
            int4 ev;
            int* evp = reinterpret_cast<int*>(&ev);
            const int j0 = (tid + q * 64) * 4;
            #pragma unroll
            for (int jj = 0; jj < 4; ++jj) {
                const int j  = j0 + jj;
                const int u  = j - 768;
                const int uc = u < 0 ? 0 : u;
                int idx = ((uc + 1) * 257) >> 12;
                idx = idx > 15 ? 15 : idx;
                const int c0 = (int)cf[idx * 3 + 0];
                const int c1 = (int)cf[idx * 3 + 1];
                const int c2 = (int)cf[idx * 3 + 2];
                const int xi = j - 896;
                const int r1 = c2 * xi + c1;
                long long r2 = (long long)r1 * xi + c0;
                if (r2 < 0) r2 = 0;
                evp[jj] = (int)(r2 >> 15);
            }
            se4[tid + q * 64] = ev;
        }
    }
    // NO __syncthreads: LDS written and read by this wave only (lgkmcnt-ordered)

    // exact floor(x/s), f32 only (validated absmax=0 since R6)
    auto fdiv_floor = [&](float xk) -> int {
        float nf = floorf(xk * ry);                 // candidate, off by <=1
        const float d = fmaf(-s, nf, xk);           // sign(x - nf*s) exact
        nf = (d < 0.0f) ? nf - 1.0f : nf;
        const float u = fmaf(-s, nf + 1.0f, xk);    // sign(x - (nf+1)s) exact
        nf = (u >= 0.0f) ? nf + 1.0f : nf;
        return (int)nf;
    };

    nfloat4* ob = reinterpret_cast<nfloat4*>(out) + row0 * (ROWLEN / 4);

    // ---- per-row pipeline, byte-identical math to R15 ----
    auto process = [&](const float4& va, const float4& vb, int obase) {
        const float xv[8] = {va.x, va.y, va.z, va.w, vb.x, vb.y, vb.z, vb.w};

        // row max AND min on RAW x via DPP (monotonicity of floor(./s))
        float mf = fmaxf(fmaxf(fmaxf(xv[0], xv[1]), fmaxf(xv[2], xv[3])),
                         fmaxf(fmaxf(xv[4], xv[5]), fmaxf(xv[6], xv[7])));
        float nf_ = fminf(fminf(fminf(xv[0], xv[1]), fminf(xv[2], xv[3])),
                          fminf(fminf(xv[4], xv[5]), fminf(xv[6], xv[7])));
        DPP_MAX_F32_STEP(mf, 0x111, 0xf)  DPP_MIN_F32_STEP(nf_, 0x111, 0xf)
        DPP_MAX_F32_STEP(mf, 0x112, 0xf)  DPP_MIN_F32_STEP(nf_, 0x112, 0xf)
        DPP_MAX_F32_STEP(mf, 0x114, 0xf)  DPP_MIN_F32_STEP(nf_, 0x114, 0xf)
        DPP_MAX_F32_STEP(mf, 0x118, 0xf)  DPP_MIN_F32_STEP(nf_, 0x118, 0xf)
        DPP_MAX_F32_STEP(mf, 0x142, 0xa)  DPP_MIN_F32_STEP(nf_, 0x142, 0xa)
        DPP_MAX_F32_STEP(mf, 0x143, 0xc)  DPP_MIN_F32_STEP(nf_, 0x143, 0xc)
        const float xmax = __int_as_float(__builtin_amdgcn_readlane(__float_as_int(mf), 63));
        const float xmin = __int_as_float(__builtin_amdgcn_readlane(__float_as_int(nf_), 63));

        int n[8];
        #pragma unroll
        for (int k = 0; k < 8; ++k) n[k] = fdiv_floor(xv[k]);
        const int mx = fdiv_floor(xmax);            // uniform across lanes
        const int mn = fdiv_floor(xmin);

        const int joff = 1023 - mx;                 // j = n + joff, j <= 1023

        int e[8];
        int tsum = 0;
        if (mn + joff >= 0) {
            // fast path: whole row inside the LUT domain
            #pragma unroll
            for (int k = 0; k < 8; ++k) {
                e[k] = s_e[n[k] + joff];            // one ds_read_b32
                tsum += e[k];
            }
        } else {
            // rare exact fallback: row span > 1023 -> full Horner at actual xi
            #pragma unroll
            for (int k = 0; k < 8; ++k) {
                const int u  = n[k] + (255 - mx);
                const int uc = u < 0 ? 0 : u;
                int idx = ((uc + 1) * 257) >> 12;
                idx = idx > 15 ? 15 : idx;
                const int4 c = s_cf[idx];
                const long long xi = (long long)(u - 128);
                long long r2 = ((long long)c.z * xi + c.y) * xi + c.x;  // exact i64
                if (r2 < 0) r2 = 0;
                e[k] = (int)(r2 >> 15);
                tsum += e[k];
            }
        }

        DPP_SUM_I32(tsum)
        int ts = __builtin_amdgcn_readlane(tsum, 63);
        if (ts < 1) ts = 1;

        // factor = floor(RN64(2^32/exp_sum)) == numpy; fits u32 (sum >= ~2^13)
        const unsigned int factor =
            (unsigned int)floor(__ddiv_rn(4294967296.0, (double)ts));

        // softmax_int = (e*factor)>>25, exact u64; out = si * 2^-7
        nfloat4 o0, o1;
        #pragma unroll
        for (int k = 0; k < 4; ++k) {
            const unsigned long long p0 = (unsigned long long)(unsigned int)e[k]   * factor;
            const unsigned long long p1 = (unsigned long long)(unsigned int)e[k+4] * factor;
            o0[k] = (float)(int)(p0 >> 25) * 0.0078125f;
            o1[k] = (float)(int)(p1 >> 25) * 0.0078125f;
        }

        ob[obase + tid]      = o0;      // plain stores (R14: == NT)
        ob[obase + tid + 64] = o1;
    };

    // ---- rolling schedule: depth-2 lookahead, issue pinned via sched_barrier ----
    float4 a2 = xp[256 + tid];
    float4 b2 = xp[256 + 64 + tid];
    __builtin_amdgcn_sched_barrier(0);      // row2 loads may not sink below
    process(a0, b0, 0);

    float4 a3 = xp[384 + tid];
    float4 b3 = xp[384 + 64 + tid];
    __builtin_amdgcn_sched_barrier(0);      // row3 loads may not sink below
    process(a1, b1, 128);

    process(a2, b2, 256);
    process(a3, b3, 384);

    if (row0 == 0 && tid == 0)
        out[(long long)nrows * ROWLEN] = 0.0078125f;   // second output: s_out
}

extern "C" void kernel_launch(void* const* d_in, const int* in_sizes, int n_in,
                              void* d_out, int out_size, void* d_ws, size_t ws_size,
                              hipStream_t stream) {
    const float* x  = (const float*)d_in[0];
    const float* sf = (const float*)d_in[1];
    const float* lo = (const float*)d_in[2];
    const float* cf = (const float*)d_in[3];
    float* out = (float*)d_out;

    const int nrows = in_sizes[0] / ROWLEN;   // 49152

    const int has_glut = (d_ws != nullptr && ws_size >= 4096) ? 1 : 0;
    int* glut = (int*)d_ws;
    if (has_glut)
        lut_builder<<<1, 256, 0, stream>>>(cf, glut);

    // 12288 blocks of ONE wave, 4 contiguous rows each; 32 blocks/CU.
    ppis_kernel<<<nrows / 4, 64, 0, stream>>>(x, sf, lo, cf, out,
                                              glut, has_glut, nrows);
}

// Round 10
// 179.132 us; speedup vs baseline: 1.0629x; 1.0629x over previous
//
#include <hip/hip_runtime.h>

// PPolyIntSoftmax, rows of 512. Exact float64-numpy replication.
// R17 = R14 restored (final): best-measured wall-clock configuration.
//  Ledger: R10 persistence (+3.5us), R11/R12 ILP (+6us), R13 stagger (0),
//  R14 plain-vs-NT stores (0), R15 LUT hoist (-1us kernel, +4us wall from
//  the extra builder dispatch), R16 1-wave sync domain (+5us). Kernel time
//  is invariant at ~59-61us across occupancy 28-65%, VALU 25-41%, MLP 2-8
//  loads/wave, sync domain 1-4 waves -> limiter is the memory system's
//  ~2.5 TB/s mixed read+write service rate for the fixed 192 MB footprint,
//  not any HIP-level structure. Single-kernel R9 shape, plain stores.
//  Exact-integer pipeline (absmax=0): fdiv_floor two-fma correction, LUT
//  Horner (i32/i64 exact), DPP i32 sum, factor via __ddiv_rn,
//  (e*factor)>>25 exact u64.

#define ROWLEN 512

typedef float nfloat4 __attribute__((ext_vector_type(4)));

#define DPP_SUM_I32(t)                                                        \
    t += __builtin_amdgcn_update_dpp(0, t, 0x111, 0xf, 0xf, true);            \
    t += __builtin_amdgcn_update_dpp(0, t, 0x112, 0xf, 0xf, true);            \
    t += __builtin_amdgcn_update_dpp(0, t, 0x114, 0xf, 0xf, true);            \
    t += __builtin_amdgcn_update_dpp(0, t, 0x118, 0xf, 0xf, true);            \
    t += __builtin_amdgcn_update_dpp(0, t, 0x142, 0xa, 0xf, true);            \
    t += __builtin_amdgcn_update_dpp(0, t, 0x143, 0xc, 0xf, true);

#define DPP_MAX_F32_STEP(m, ctrl, rmask)                                      \
    {                                                                         \
        int _mi = __float_as_int(m);                                          \
        int _sh = __builtin_amdgcn_update_dpp(_mi, _mi, ctrl, rmask, 0xf, false); \
        m = fmaxf(m, __int_as_float(_sh));                                    \
    }
#define DPP_MIN_F32_STEP(m, ctrl, rmask)                                      \
    {                                                                         \
        int _mi = __float_as_int(m);                                          \
        int _sh = __builtin_amdgcn_update_dpp(_mi, _mi, ctrl, rmask, 0xf, false); \
        m = fminf(m, __int_as_float(_sh));                                    \
    }

__global__ __launch_bounds__(256, 8) void ppis_kernel(
    const float* __restrict__ x,
    const float* __restrict__ sfp,
    const float* __restrict__ lo,   // unused: structure derived analytically
    const float* __restrict__ cf,
    float* __restrict__ out,
    int nrows)
{
    __shared__ int  s_e[1024];   // exp_int LUT: entry j <-> xi = j - 896
    __shared__ int4 s_cf[16];    // coeffs for the rare exact-fallback path

    const int tid  = threadIdx.x;
    const int lane = tid & 63;
    const int wid  = tid >> 6;

    // ---- issue x loads first: LUT build overlaps their latency ----
    const long long row = (long long)blockIdx.x * 4 + wid;
    const float4* xp = reinterpret_cast<const float4*>(x) + row * (ROWLEN / 4);
    const float4 va = xp[lane];
    const float4 vb = xp[lane + 64];

    const float s  = sfp[0];
    const float ry = 1.0f / s;   // approx reciprocal; exactness via fma sign tests

    if (tid < 16)
        s_cf[tid] = make_int4((int)cf[tid*3+0], (int)cf[tid*3+1], (int)cf[tid*3+2], 0);

    // ---- build LUT: 4 entries/thread, bit-identical integer pipeline ----
    {
        int4 ev;
        int* evp = reinterpret_cast<int*>(&ev);
        const int j0 = tid * 4;
        #pragma unroll
        for (int jj = 0; jj < 4; ++jj) {
            const int j  = j0 + jj;
            const int u  = j - 768;              // u = xi + 128
            const int uc = u < 0 ? 0 : u;
            int idx = ((uc + 1) * 257) >> 12;    // == clip(searchsorted-1,0,15)
            idx = idx > 15 ? 15 : idx;
            const int c0 = (int)cf[idx * 3 + 0];
            const int c1 = (int)cf[idx * 3 + 1];
            const int c2 = (int)cf[idx * 3 + 2];
            const int xi = j - 896;              // UNCLAMPED xi
            const int r1 = c2 * xi + c1;               // |c2*xi| < 2^27: exact i32
            long long r2 = (long long)r1 * xi + c0;    // exact i64
            if (r2 < 0) r2 = 0;
            evp[jj] = (int)(r2 >> 15);
        }
        reinterpret_cast<int4*>(s_e)[tid] = ev;  // ds_write_b128
    }
    __syncthreads();

    const float xv[8] = {va.x, va.y, va.z, va.w, vb.x, vb.y, vb.z, vb.w};

    // row max AND min on RAW x via DPP (monotonicity of floor(./s))
    float mf = fmaxf(fmaxf(fmaxf(xv[0], xv[1]), fmaxf(xv[2], xv[3])),
                     fmaxf(fmaxf(xv[4], xv[5]), fmaxf(xv[6], xv[7])));
    float nf_ = fminf(fminf(fminf(xv[0], xv[1]), fminf(xv[2], xv[3])),
                      fminf(fminf(xv[4], xv[5]), fminf(xv[6], xv[7])));
    DPP_MAX_F32_STEP(mf, 0x111, 0xf)  DPP_MIN_F32_STEP(nf_, 0x111, 0xf)
    DPP_MAX_F32_STEP(mf, 0x112, 0xf)  DPP_MIN_F32_STEP(nf_, 0x112, 0xf)
    DPP_MAX_F32_STEP(mf, 0x114, 0xf)  DPP_MIN_F32_STEP(nf_, 0x114, 0xf)
    DPP_MAX_F32_STEP(mf, 0x118, 0xf)  DPP_MIN_F32_STEP(nf_, 0x118, 0xf)
    DPP_MAX_F32_STEP(mf, 0x142, 0xa)  DPP_MIN_F32_STEP(nf_, 0x142, 0xa)
    DPP_MAX_F32_STEP(mf, 0x143, 0xc)  DPP_MIN_F32_STEP(nf_, 0x143, 0xc)
    const float xmax = __int_as_float(__builtin_amdgcn_readlane(__float_as_int(mf), 63));
    const float xmin = __int_as_float(__builtin_amdgcn_readlane(__float_as_int(nf_), 63));

    // exact floor(x/s), f32 only
    auto fdiv_floor = [&](float xk) -> int {
        float nf = floorf(xk * ry);                 // candidate, off by <=1
        const float d = fmaf(-s, nf, xk);           // sign(x - nf*s) exact
        nf = (d < 0.0f) ? nf - 1.0f : nf;
        const float u = fmaf(-s, nf + 1.0f, xk);    // sign(x - (nf+1)s) exact
        nf = (u >= 0.0f) ? nf + 1.0f : nf;
        return (int)nf;
    };

    int n[8];
    #pragma unroll
    for (int k = 0; k < 8; ++k) n[k] = fdiv_floor(xv[k]);
    const int mx = fdiv_floor(xmax);                // uniform across lanes
    const int mn = fdiv_floor(xmin);

    const int joff = 1023 - mx;                     // j = n + joff, j <= 1023

    int e[8];
    int tsum = 0;
    if (mn + joff >= 0) {
        // fast path: whole row inside the LUT domain
        #pragma unroll
        for (int k = 0; k < 8; ++k) {
            e[k] = s_e[n[k] + joff];                // one ds_read_b32
            tsum += e[k];
        }
    } else {
        // rare exact fallback: row span > 1023 ints -> full Horner at actual xi
        #pragma unroll
        for (int k = 0; k < 8; ++k) {
            const int u  = n[k] + (255 - mx);
            const int uc = u < 0 ? 0 : u;
            int idx = ((uc + 1) * 257) >> 12;
            idx = idx > 15 ? 15 : idx;
            const int4 c = s_cf[idx];
            const long long xi = (long long)(u - 128);
            long long r2 = ((long long)c.z * xi + c.y) * xi + c.x;  // exact i64
            if (r2 < 0) r2 = 0;
            e[k] = (int)(r2 >> 15);
            tsum += e[k];
        }
    }

    DPP_SUM_I32(tsum)
    int ts = __builtin_amdgcn_readlane(tsum, 63);
    if (ts < 1) ts = 1;

    // factor = floor(RN64(2^32/exp_sum)) == numpy; fits u32 (sum >= ~2^13)
    const unsigned int factor =
        (unsigned int)floor(__ddiv_rn(4294967296.0, (double)ts));

    // softmax_int = (e*factor)>>25, exact u64; out = si * 2^-7
    nfloat4 o0, o1;
    #pragma unroll
    for (int k = 0; k < 4; ++k) {
        const unsigned long long p0 = (unsigned long long)(unsigned int)e[k]   * factor;
        const unsigned long long p1 = (unsigned long long)(unsigned int)e[k+4] * factor;
        o0[k] = (float)(int)(p0 >> 25) * 0.0078125f;
        o1[k] = (float)(int)(p1 >> 25) * 0.0078125f;
    }

    nfloat4* op = reinterpret_cast<nfloat4*>(out) + row * (ROWLEN / 4);
    op[lane]      = o0;     // plain stores (R14 A/B: == NT stores)
    op[lane + 64] = o1;

    if (row == 0 && lane == 0)
        out[(long long)nrows * ROWLEN] = 0.0078125f;   // second output: s_out
}

extern "C" void kernel_launch(void* const* d_in, const int* in_sizes, int n_in,
                              void* d_out, int out_size, void* d_ws, size_t ws_size,
                              hipStream_t stream) {
    const float* x  = (const float*)d_in[0];
    const float* sf = (const float*)d_in[1];
    const float* lo = (const float*)d_in[2];
    const float* cf = (const float*)d_in[3];
    float* out = (float*)d_out;

    const int nrows = in_sizes[0] / ROWLEN;   // 49152
    ppis_kernel<<<nrows / 4, 256, 0, stream>>>(x, sf, lo, cf, out, nrows);
}